// Round 18
// baseline (445.302 us; speedup 1.0000x reference)
//
#include <hip/hip_runtime.h>
#include <hip/hip_bf16.h>
#include <hip/hip_fp16.h>

#define BATCH 16384
#define NM 9
#define ND 512
#define BM 64
#define NKT 16          // k-tiles of 32
#define NTHREADS 512
#define WMAT ((size_t)ND * ND)   // 262144 elems per weight matrix

typedef __bf16 bf16x8 __attribute__((ext_vector_type(8)));
typedef float  f32x4  __attribute__((ext_vector_type(4)));

// ---------------- K0: W[m][d][e] (fp32) -> MFMA-native tiled bf16 ----------------
// Fragment block for (kt, c16) = 1KB laid out in lane order, so K1's wave
// load is base + lane*16 : fully coalesced.
__global__ __launch_bounds__(256)
void prep_weights(const float* __restrict__ Wi, const float* __restrict__ We,
                  __hip_bfloat16* __restrict__ WiT, __hip_bfloat16* __restrict__ WeT) {
  const int z  = blockIdx.y;           // 0..17: matrix select
  const int kt = blockIdx.x;           // 0..15
  const float* src;
  __hip_bfloat16* dst;
  if (z < NM) { src = Wi + (size_t)z * WMAT;        dst = WiT + (size_t)z * WMAT; }
  else        { src = We + (size_t)(z - NM) * WMAT; dst = WeT + (size_t)(z - NM) * WMAT; }
  const int wave = threadIdx.x >> 6;
  const int lane = threadIdx.x & 63;
  const int k0   = kt * 32 + (lane >> 4) * 8;
  #pragma unroll
  for (int g = wave; g < 32; g += 4) {          // c16 group
    const int col = g * 16 + (lane & 15);
    bf16x8 v;
    #pragma unroll
    for (int j = 0; j < 8; ++j)
      v[j] = (__bf16)src[(size_t)(k0 + j) * ND + col];
    *(bf16x8*)(dst + (size_t)(kt * 32 + g) * 512 + lane * 8) = v;
  }
}

// ---------------- K1: per-(btile,m) dual GEMM + sigmoid/L1 gate + relu ----------------
// R8 champion structure; R18: __launch_bounds__(512,3) -> ~170 regs/wave
// (12 waves/CU) so the depth-3 B prefetch + af dbuf survives regalloc.
__global__ __launch_bounds__(NTHREADS, 3)
void gemm_kernel(const float* __restrict__ x,
                 const __hip_bfloat16* __restrict__ WiT,
                 const __hip_bfloat16* __restrict__ WeT,
                 const float* __restrict__ bi,
                 const float* __restrict__ be,
                 float* __restrict__ out) {
  __shared__ union {
    __hip_bfloat16 xs[BM][ND + 8];   // 1040B row stride
    __half         gs[BM][ND + 8];   // g repack buffer
  } sh;
  __shared__ float alphaW[8][BM];
  __shared__ float alphaV[BM];

  const int tid  = threadIdx.x;
  const int wave = tid >> 6;
  const int lane = tid & 63;
  const int l15  = lane & 15;
  const int l4   = lane >> 4;

  // XCD-m clustering decode (bijective: (m, bx) covers 9 x 256)
  const int bid = blockIdx.x;          // 0..2303
  const int q   = bid >> 3;            // 0..287
  const int m   = q >> 5;              // 0..8
  const int bx  = (bid & 7) + ((q & 31) << 3);
  const int b0  = bx * BM;
  const int wn0 = wave * 64;

  float* alpha_out = out + (size_t)BATCH * NM * ND;

  // wave's fragment bases: c16 groups [wave*4 .. wave*4+3], per-lane 16B slot
  const __hip_bfloat16* bpi = WiT + (size_t)m * WMAT + (size_t)wave * 4 * 512 + lane * 8;
  const __hip_bfloat16* bpe = WeT + (size_t)m * WMAT + (size_t)wave * 4 * 512 + lane * 8;

  bf16x8 breg[3][4];
  bf16x8 afr[2][4];

  // pass-0 B prologue: 12 loads in flight during x staging
  #pragma unroll
  for (int d = 0; d < 3; ++d)
    #pragma unroll
    for (int nt = 0; nt < 4; ++nt)
      breg[d][nt] = *(const bf16x8*)(bpi + (size_t)d * 16384 + nt * 512);

  // ---- stage X tile: fp32 global -> bf16 LDS ----
  #pragma unroll
  for (int it = 0; it < (BM * ND / 4) / NTHREADS; ++it) {
    int idx = it * NTHREADS + tid;
    int r   = idx >> 7;
    int c4  = (idx & 127) * 4;
    float4 v = *(const float4*)(x + (size_t)(b0 + r) * (NM * ND) + m * ND + c4);
    union { ushort4 u; __hip_bfloat16 h[4]; } p;
    p.h[0] = __float2bfloat16(v.x);
    p.h[1] = __float2bfloat16(v.y);
    p.h[2] = __float2bfloat16(v.z);
    p.h[3] = __float2bfloat16(v.w);
    *(ushort4*)&sh.xs[r][c4] = p.u;
  }
  __syncthreads();

  f32x4 acc[4][4];
  #pragma unroll
  for (int a = 0; a < 4; ++a)
    #pragma unroll
    for (int c = 0; c < 4; ++c) acc[a][c] = (f32x4){0.f, 0.f, 0.f, 0.f};

  // pass-0 af prologue
  #pragma unroll
  for (int mt = 0; mt < 4; ++mt)
    afr[0][mt] = *(const bf16x8*)&sh.xs[mt * 16 + l15][l4 * 8];

  // ================= pass 0 : Wi =================
  #pragma unroll
  for (int kt = 0; kt < NKT; ++kt) {
    if (kt + 1 < NKT) {
      const int kb = (kt + 1) * 32 + l4 * 8;
      #pragma unroll
      for (int mt = 0; mt < 4; ++mt)
        afr[(kt + 1) & 1][mt] = *(const bf16x8*)&sh.xs[mt * 16 + l15][kb];
    }
    #pragma unroll
    for (int mt = 0; mt < 4; ++mt)
      #pragma unroll
      for (int nt = 0; nt < 4; ++nt)
        acc[mt][nt] = __builtin_amdgcn_mfma_f32_16x16x32_bf16(afr[kt & 1][mt], breg[kt % 3][nt], acc[mt][nt], 0, 0, 0);
    if (kt + 3 < NKT) {   // refill the buffer just freed (WAR keeps it after MFMAs)
      const size_t off = (size_t)(kt + 3) * 16384;
      #pragma unroll
      for (int nt = 0; nt < 4; ++nt)
        breg[kt % 3][nt] = *(const bf16x8*)(bpi + off + nt * 512);
    }
  }

  // pass-1 B prologue: issue before sigmoid VALU work
  #pragma unroll
  for (int d = 0; d < 3; ++d)
    #pragma unroll
    for (int nt = 0; nt < 4; ++nt)
      breg[d][nt] = *(const bf16x8*)(bpe + (size_t)d * 16384 + nt * 512);

  // ---- per-wave sigmoid partial sums (no barrier; reduce deferred) ----
  {
    float biv[4];
    #pragma unroll
    for (int nt = 0; nt < 4; ++nt) biv[nt] = bi[m * ND + wn0 + nt * 16 + l15];
    #pragma unroll
    for (int mt = 0; mt < 4; ++mt)
      #pragma unroll
      for (int r = 0; r < 4; ++r) {
        float s = 0.f;
        #pragma unroll
        for (int nt = 0; nt < 4; ++nt) {
          float t = acc[mt][nt][r] + biv[nt];
          s += 1.f / (1.f + __expf(-t));
        }
        s += __shfl_xor(s, 1, 16);
        s += __shfl_xor(s, 2, 16);
        s += __shfl_xor(s, 4, 16);
        s += __shfl_xor(s, 8, 16);
        if (l15 == 0) alphaW[wave][mt * 16 + l4 * 4 + r] = s;
      }
  }

  // ================= pass 1 : We (xs resident, barrier-free) =================
  #pragma unroll
  for (int a = 0; a < 4; ++a)
    #pragma unroll
    for (int c = 0; c < 4; ++c) acc[a][c] = (f32x4){0.f, 0.f, 0.f, 0.f};

  #pragma unroll
  for (int mt = 0; mt < 4; ++mt)
    afr[0][mt] = *(const bf16x8*)&sh.xs[mt * 16 + l15][l4 * 8];

  #pragma unroll
  for (int kt = 0; kt < NKT; ++kt) {
    if (kt + 1 < NKT) {
      const int kb = (kt + 1) * 32 + l4 * 8;
      #pragma unroll
      for (int mt = 0; mt < 4; ++mt)
        afr[(kt + 1) & 1][mt] = *(const bf16x8*)&sh.xs[mt * 16 + l15][kb];
    }
    #pragma unroll
    for (int mt = 0; mt < 4; ++mt)
      #pragma unroll
      for (int nt = 0; nt < 4; ++nt)
        acc[mt][nt] = __builtin_amdgcn_mfma_f32_16x16x32_bf16(afr[kt & 1][mt], breg[kt % 3][nt], acc[mt][nt], 0, 0, 0);
    if (kt + 3 < NKT) {
      const size_t off = (size_t)(kt + 3) * 16384;
      #pragma unroll
      for (int nt = 0; nt < 4; ++nt)
        breg[kt % 3][nt] = *(const bf16x8*)(bpe + off + nt * 512);
    }
  }

  __syncthreads();   // alphaW visible to all; all waves done reading sh.xs

  // ---- alpha reduce + output ----
  if (tid < BM) {
    float a = 0.f;
    #pragma unroll
    for (int w = 0; w < 8; ++w) a += alphaW[w][tid];
    alphaV[tid] = a;
    alpha_out[(size_t)(b0 + tid) * NM + m] = a;
  }
  __syncthreads();

  // ---- g = relu(alpha * t_e + be): LDS repack, then coalesced 16B stores ----
  {
    float bev[4];
    #pragma unroll
    for (int nt = 0; nt < 4; ++nt) bev[nt] = be[m * ND + wn0 + nt * 16 + l15];
    #pragma unroll
    for (int mt = 0; mt < 4; ++mt)
      #pragma unroll
      for (int r = 0; r < 4; ++r) {
        const int row = mt * 16 + l4 * 4 + r;
        const float al = alphaV[row];
        #pragma unroll
        for (int nt = 0; nt < 4; ++nt) {
          float t = fmaxf(al * acc[mt][nt][r] + bev[nt], 0.f);
          sh.gs[row][wn0 + nt * 16 + l15] = __float2half(t);
        }
      }
    __syncthreads();
    // wave w stores rows w, w+8, ..., w+56; each lane moves 16B (8 halves)
    #pragma unroll
    for (int i = 0; i < 8; ++i) {
      const int row = wave + i * 8;
      __half* gd = (__half*)((char*)out + (size_t)(b0 + row) * (NM * ND * 4)) + m * ND;
      *(uint4*)(gd + lane * 8) = *(const uint4*)&sh.gs[row][lane * 8];
    }
  }
}

// ---------------- K2: inter-branch affinity + aggregation ----------------
// v3: 512 threads / 8 waves (measured at floor; frozen).
__global__ __launch_bounds__(512)
void inter_kernel(float* __restrict__ out) {
  __shared__ float gs[NM][ND + 8];
  __shared__ float Gr[45];
  __shared__ float aff[NM][NM];
  const int b = blockIdx.x;
  const int tid = threadIdx.x;
  const __half* gsrc = (const __half*)((const char*)out + (size_t)b * (NM * ND * 4));

  for (int i = tid; i < NM * ND / 8; i += 512) {
    union { uint4 u; __half h[8]; } p;
    p.u = *(const uint4*)(gsrc + (size_t)i * 8);
    const int m = i >> 6;
    const int e = (i & 63) * 8;
    #pragma unroll
    for (int j = 0; j < 8; ++j) gs[m][e + j] = __half2float(p.h[j]);
  }
  __syncthreads();

  const int wave = tid >> 6, lane = tid & 63;
  for (int pr = wave; pr < 45; pr += 8) {
    int a = 0, qq = pr;
    while (qq >= NM - a) { qq -= NM - a; ++a; }
    const int bb = a + qq;
    float s = 0.f;
    #pragma unroll
    for (int j = 0; j < 8; ++j) s += gs[a][lane + 64 * j] * gs[bb][lane + 64 * j];
    #pragma unroll
    for (int off = 1; off < 64; off <<= 1) s += __shfl_xor(s, off, 64);
    if (lane == 0) Gr[pr] = s;
  }
  __syncthreads();

  if (tid < NM * NM) {
    const int mm = tid / NM, nn = tid % NM;
    float v = 0.f;
    if (mm != nn) {
      const int a = mm < nn ? mm : nn;
      const int c = mm < nn ? nn : mm;
      auto tri = [](int t) { return t * NM - (t * (t - 1)) / 2; };
      float d2 = Gr[tri(mm)] + Gr[tri(nn)] - 2.f * Gr[tri(a) + (c - a)];
      d2 = fmaxf(d2, 0.f);
      v = tanhf(sqrtf(d2));
    }
    aff[tid / NM][tid % NM] = v;
  }
  __syncthreads();

  float* od = out + (size_t)b * (NM * ND);
  for (int i = tid; i < NM * ND / 4; i += 512) {
    const int mm = i >> 7;
    const int e4 = (i & 127) * 4;
    float4 r = {0.f, 0.f, 0.f, 0.f};
    #pragma unroll
    for (int n = 0; n < NM; ++n) {
      const float a = aff[mm][n];
      const float4 gv = *(const float4*)&gs[n][e4];
      r.x += a * gv.x; r.y += a * gv.y; r.z += a * gv.z; r.w += a * gv.w;
    }
    const float4 gm = *(const float4*)&gs[mm][e4];
    r.x = 0.5f * (gm.x + r.x);
    r.y = 0.5f * (gm.y + r.y);
    r.z = 0.5f * (gm.z + r.z);
    r.w = 0.5f * (gm.w + r.w);
    *(float4*)(od + (size_t)mm * ND + e4) = r;
  }
}

extern "C" void kernel_launch(void* const* d_in, const int* in_sizes, int n_in,
                              void* d_out, int out_size, void* d_ws, size_t ws_size,
                              hipStream_t stream) {
  const float* x  = (const float*)d_in[0];
  const float* Wi = (const float*)d_in[1];
  const float* bi = (const float*)d_in[2];
  const float* We = (const float*)d_in[3];
  const float* be = (const float*)d_in[4];
  float* out = (float*)d_out;

  __hip_bfloat16* WiT = (__hip_bfloat16*)d_ws;
  __hip_bfloat16* WeT = WiT + (size_t)NM * ND * ND;

  prep_weights<<<dim3(NKT, 2 * NM), 256, 0, stream>>>(Wi, We, WiT, WeT);
  gemm_kernel<<<BATCH / BM * NM, NTHREADS, 0, stream>>>(x, WiT, WeT, bi, be, out);
  inter_kernel<<<BATCH, 512, 0, stream>>>(out);
}

// Round 19
// 365.173 us; speedup vs baseline: 1.2194x; 1.2194x over previous
//
#include <hip/hip_runtime.h>
#include <hip/hip_bf16.h>
#include <hip/hip_fp16.h>

#define BATCH 16384
#define NM 9
#define ND 512
#define BM 64
#define NKT 16          // k-tiles of 32
#define NTHREADS 512
#define WMAT ((size_t)ND * ND)   // 262144 elems per weight matrix

typedef __bf16 bf16x8 __attribute__((ext_vector_type(8)));
typedef float  f32x4  __attribute__((ext_vector_type(4)));

// ---------------- K0: W[m][d][e] (fp32) -> MFMA-native tiled bf16 ----------------
// Fragment block for (kt, c16) = 1KB laid out in lane order, so K1's wave
// load is base + lane*16 : fully coalesced.
__global__ __launch_bounds__(256)
void prep_weights(const float* __restrict__ Wi, const float* __restrict__ We,
                  __hip_bfloat16* __restrict__ WiT, __hip_bfloat16* __restrict__ WeT) {
  const int z  = blockIdx.y;           // 0..17: matrix select
  const int kt = blockIdx.x;           // 0..15
  const float* src;
  __hip_bfloat16* dst;
  if (z < NM) { src = Wi + (size_t)z * WMAT;        dst = WiT + (size_t)z * WMAT; }
  else        { src = We + (size_t)(z - NM) * WMAT; dst = WeT + (size_t)(z - NM) * WMAT; }
  const int wave = threadIdx.x >> 6;
  const int lane = threadIdx.x & 63;
  const int k0   = kt * 32 + (lane >> 4) * 8;
  #pragma unroll
  for (int g = wave; g < 32; g += 4) {          // c16 group
    const int col = g * 16 + (lane & 15);
    bf16x8 v;
    #pragma unroll
    for (int j = 0; j < 8; ++j)
      v[j] = (__bf16)src[(size_t)(k0 + j) * ND + col];
    *(bf16x8*)(dst + (size_t)(kt * 32 + g) * 512 + lane * 8) = v;
  }
}

// ---------------- K1: per-(btile,m) dual GEMM + sigmoid/L1 gate + relu ----------------
// R8 champion structure (FROZEN; measured plateau of this fused structure):
// 1-D grid 2304, XCD-m clustering, 8 waves x 64 cols, depth-3 direct-into-
// buffer B prefetch, af double-buffer, deferred alpha reduce, LDS g-repack.
__global__ __launch_bounds__(NTHREADS, 4)
void gemm_kernel(const float* __restrict__ x,
                 const __hip_bfloat16* __restrict__ WiT,
                 const __hip_bfloat16* __restrict__ WeT,
                 const float* __restrict__ bi,
                 const float* __restrict__ be,
                 float* __restrict__ out) {
  __shared__ union {
    __hip_bfloat16 xs[BM][ND + 8];   // 1040B row stride
    __half         gs[BM][ND + 8];   // g repack buffer
  } sh;
  __shared__ float alphaW[8][BM];
  __shared__ float alphaV[BM];

  const int tid  = threadIdx.x;
  const int wave = tid >> 6;
  const int lane = tid & 63;
  const int l15  = lane & 15;
  const int l4   = lane >> 4;

  // XCD-m clustering decode (bijective: (m, bx) covers 9 x 256)
  const int bid = blockIdx.x;          // 0..2303
  const int q   = bid >> 3;            // 0..287
  const int m   = q >> 5;              // 0..8
  const int bx  = (bid & 7) + ((q & 31) << 3);
  const int b0  = bx * BM;
  const int wn0 = wave * 64;

  float* alpha_out = out + (size_t)BATCH * NM * ND;

  // wave's fragment bases: c16 groups [wave*4 .. wave*4+3], per-lane 16B slot
  const __hip_bfloat16* bpi = WiT + (size_t)m * WMAT + (size_t)wave * 4 * 512 + lane * 8;
  const __hip_bfloat16* bpe = WeT + (size_t)m * WMAT + (size_t)wave * 4 * 512 + lane * 8;

  bf16x8 breg[3][4];
  bf16x8 afr[2][4];

  // pass-0 B prologue: 12 loads in flight during x staging
  #pragma unroll
  for (int d = 0; d < 3; ++d)
    #pragma unroll
    for (int nt = 0; nt < 4; ++nt)
      breg[d][nt] = *(const bf16x8*)(bpi + (size_t)d * 16384 + nt * 512);

  // ---- stage X tile: fp32 global -> bf16 LDS ----
  #pragma unroll
  for (int it = 0; it < (BM * ND / 4) / NTHREADS; ++it) {
    int idx = it * NTHREADS + tid;
    int r   = idx >> 7;
    int c4  = (idx & 127) * 4;
    float4 v = *(const float4*)(x + (size_t)(b0 + r) * (NM * ND) + m * ND + c4);
    union { ushort4 u; __hip_bfloat16 h[4]; } p;
    p.h[0] = __float2bfloat16(v.x);
    p.h[1] = __float2bfloat16(v.y);
    p.h[2] = __float2bfloat16(v.z);
    p.h[3] = __float2bfloat16(v.w);
    *(ushort4*)&sh.xs[r][c4] = p.u;
  }
  __syncthreads();

  f32x4 acc[4][4];
  #pragma unroll
  for (int a = 0; a < 4; ++a)
    #pragma unroll
    for (int c = 0; c < 4; ++c) acc[a][c] = (f32x4){0.f, 0.f, 0.f, 0.f};

  // pass-0 af prologue
  #pragma unroll
  for (int mt = 0; mt < 4; ++mt)
    afr[0][mt] = *(const bf16x8*)&sh.xs[mt * 16 + l15][l4 * 8];

  // ================= pass 0 : Wi =================
  #pragma unroll
  for (int kt = 0; kt < NKT; ++kt) {
    if (kt + 1 < NKT) {
      const int kb = (kt + 1) * 32 + l4 * 8;
      #pragma unroll
      for (int mt = 0; mt < 4; ++mt)
        afr[(kt + 1) & 1][mt] = *(const bf16x8*)&sh.xs[mt * 16 + l15][kb];
    }
    #pragma unroll
    for (int mt = 0; mt < 4; ++mt)
      #pragma unroll
      for (int nt = 0; nt < 4; ++nt)
        acc[mt][nt] = __builtin_amdgcn_mfma_f32_16x16x32_bf16(afr[kt & 1][mt], breg[kt % 3][nt], acc[mt][nt], 0, 0, 0);
    if (kt + 3 < NKT) {   // refill the buffer just freed (WAR keeps it after MFMAs)
      const size_t off = (size_t)(kt + 3) * 16384;
      #pragma unroll
      for (int nt = 0; nt < 4; ++nt)
        breg[kt % 3][nt] = *(const bf16x8*)(bpi + off + nt * 512);
    }
  }

  // pass-1 B prologue: issue before sigmoid VALU work
  #pragma unroll
  for (int d = 0; d < 3; ++d)
    #pragma unroll
    for (int nt = 0; nt < 4; ++nt)
      breg[d][nt] = *(const bf16x8*)(bpe + (size_t)d * 16384 + nt * 512);

  // ---- per-wave sigmoid partial sums (no barrier; reduce deferred) ----
  {
    float biv[4];
    #pragma unroll
    for (int nt = 0; nt < 4; ++nt) biv[nt] = bi[m * ND + wn0 + nt * 16 + l15];
    #pragma unroll
    for (int mt = 0; mt < 4; ++mt)
      #pragma unroll
      for (int r = 0; r < 4; ++r) {
        float s = 0.f;
        #pragma unroll
        for (int nt = 0; nt < 4; ++nt) {
          float t = acc[mt][nt][r] + biv[nt];
          s += 1.f / (1.f + __expf(-t));
        }
        s += __shfl_xor(s, 1, 16);
        s += __shfl_xor(s, 2, 16);
        s += __shfl_xor(s, 4, 16);
        s += __shfl_xor(s, 8, 16);
        if (l15 == 0) alphaW[wave][mt * 16 + l4 * 4 + r] = s;
      }
  }

  // ================= pass 1 : We (xs resident, barrier-free) =================
  #pragma unroll
  for (int a = 0; a < 4; ++a)
    #pragma unroll
    for (int c = 0; c < 4; ++c) acc[a][c] = (f32x4){0.f, 0.f, 0.f, 0.f};

  #pragma unroll
  for (int mt = 0; mt < 4; ++mt)
    afr[0][mt] = *(const bf16x8*)&sh.xs[mt * 16 + l15][l4 * 8];

  #pragma unroll
  for (int kt = 0; kt < NKT; ++kt) {
    if (kt + 1 < NKT) {
      const int kb = (kt + 1) * 32 + l4 * 8;
      #pragma unroll
      for (int mt = 0; mt < 4; ++mt)
        afr[(kt + 1) & 1][mt] = *(const bf16x8*)&sh.xs[mt * 16 + l15][kb];
    }
    #pragma unroll
    for (int mt = 0; mt < 4; ++mt)
      #pragma unroll
      for (int nt = 0; nt < 4; ++nt)
        acc[mt][nt] = __builtin_amdgcn_mfma_f32_16x16x32_bf16(afr[kt & 1][mt], breg[kt % 3][nt], acc[mt][nt], 0, 0, 0);
    if (kt + 3 < NKT) {
      const size_t off = (size_t)(kt + 3) * 16384;
      #pragma unroll
      for (int nt = 0; nt < 4; ++nt)
        breg[kt % 3][nt] = *(const bf16x8*)(bpe + off + nt * 512);
    }
  }

  __syncthreads();   // alphaW visible to all; all waves done reading sh.xs

  // ---- alpha reduce + output ----
  if (tid < BM) {
    float a = 0.f;
    #pragma unroll
    for (int w = 0; w < 8; ++w) a += alphaW[w][tid];
    alphaV[tid] = a;
    alpha_out[(size_t)(b0 + tid) * NM + m] = a;
  }
  __syncthreads();

  // ---- g = relu(alpha * t_e + be): LDS repack, then coalesced 16B stores ----
  {
    float bev[4];
    #pragma unroll
    for (int nt = 0; nt < 4; ++nt) bev[nt] = be[m * ND + wn0 + nt * 16 + l15];
    #pragma unroll
    for (int mt = 0; mt < 4; ++mt)
      #pragma unroll
      for (int r = 0; r < 4; ++r) {
        const int row = mt * 16 + l4 * 4 + r;
        const float al = alphaV[row];
        #pragma unroll
        for (int nt = 0; nt < 4; ++nt) {
          float t = fmaxf(al * acc[mt][nt][r] + bev[nt], 0.f);
          sh.gs[row][wn0 + nt * 16 + l15] = __float2half(t);
        }
      }
    __syncthreads();
    // wave w stores rows w, w+8, ..., w+56; each lane moves 16B (8 halves)
    #pragma unroll
    for (int i = 0; i < 8; ++i) {
      const int row = wave + i * 8;
      __half* gd = (__half*)((char*)out + (size_t)(b0 + row) * (NM * ND * 4)) + m * ND;
      *(uint4*)(gd + lane * 8) = *(const uint4*)&sh.gs[row][lane * 8];
    }
  }
}

// ---------------- K2: inter-branch affinity + aggregation ----------------
// v2 (best measured): 256 threads, 16B g loads, float4 LDS aggregation.
__global__ __launch_bounds__(256)
void inter_kernel(float* __restrict__ out) {
  __shared__ float gs[NM][ND + 8];
  __shared__ float Gr[45];
  __shared__ float aff[NM][NM];
  const int b = blockIdx.x;
  const int tid = threadIdx.x;
  const __half* gsrc = (const __half*)((const char*)out + (size_t)b * (NM * ND * 4));

  // load g: 16B per thread per iter (8 halves)
  for (int i = tid; i < NM * ND / 8; i += 256) {
    union { uint4 u; __half h[8]; } p;
    p.u = *(const uint4*)(gsrc + (size_t)i * 8);
    const int m = i >> 6;
    const int e = (i & 63) * 8;
    #pragma unroll
    for (int j = 0; j < 8; ++j) gs[m][e + j] = __half2float(p.h[j]);
  }
  __syncthreads();

  // 45 upper-triangular pair dot-products (incl. diagonal = sq)
  const int wave = tid >> 6, lane = tid & 63;
  for (int pr = wave; pr < 45; pr += 4) {
    int a = 0, qq = pr;
    while (qq >= NM - a) { qq -= NM - a; ++a; }
    const int bb = a + qq;
    float s = 0.f;
    #pragma unroll
    for (int j = 0; j < 8; ++j) s += gs[a][lane + 64 * j] * gs[bb][lane + 64 * j];
    #pragma unroll
    for (int off = 1; off < 64; off <<= 1) s += __shfl_xor(s, off, 64);
    if (lane == 0) Gr[pr] = s;
  }
  __syncthreads();

  if (tid < NM * NM) {
    const int mm = tid / NM, nn = tid % NM;
    float v = 0.f;
    if (mm != nn) {
      const int a = mm < nn ? mm : nn;
      const int c = mm < nn ? nn : mm;
      auto tri = [](int t) { return t * NM - (t * (t - 1)) / 2; };
      float d2 = Gr[tri(mm)] + Gr[tri(nn)] - 2.f * Gr[tri(a) + (c - a)];
      d2 = fmaxf(d2, 0.f);
      v = tanhf(sqrtf(d2));
    }
    aff[tid / NM][tid % NM] = v;
  }
  __syncthreads();

  float* od = out + (size_t)b * (NM * ND);
  for (int i = tid; i < NM * ND / 4; i += 256) {
    const int mm = i >> 7;
    const int e4 = (i & 127) * 4;
    float4 r = {0.f, 0.f, 0.f, 0.f};
    #pragma unroll
    for (int n = 0; n < NM; ++n) {
      const float a = aff[mm][n];
      const float4 gv = *(const float4*)&gs[n][e4];
      r.x += a * gv.x; r.y += a * gv.y; r.z += a * gv.z; r.w += a * gv.w;
    }
    const float4 gm = *(const float4*)&gs[mm][e4];
    r.x = 0.5f * (gm.x + r.x);
    r.y = 0.5f * (gm.y + r.y);
    r.z = 0.5f * (gm.z + r.z);
    r.w = 0.5f * (gm.w + r.w);
    *(float4*)(od + (size_t)mm * ND + e4) = r;
  }
}

extern "C" void kernel_launch(void* const* d_in, const int* in_sizes, int n_in,
                              void* d_out, int out_size, void* d_ws, size_t ws_size,
                              hipStream_t stream) {
  const float* x  = (const float*)d_in[0];
  const float* Wi = (const float*)d_in[1];
  const float* bi = (const float*)d_in[2];
  const float* We = (const float*)d_in[3];
  const float* be = (const float*)d_in[4];
  float* out = (float*)d_out;

  __hip_bfloat16* WiT = (__hip_bfloat16*)d_ws;
  __hip_bfloat16* WeT = WiT + (size_t)NM * ND * ND;

  prep_weights<<<dim3(NKT, 2 * NM), 256, 0, stream>>>(Wi, We, WiT, WeT);
  gemm_kernel<<<BATCH / BM * NM, NTHREADS, 0, stream>>>(x, WiT, WeT, bi, be, out);
  inter_kernel<<<BATCH, 256, 0, stream>>>(out);
}